// Round 9
// baseline (220.929 us; speedup 1.0000x reference)
//
#include <hip/hip_runtime.h>

#define ST 512           // threads, scatter kernel
#define EPB 8192         // edges per scatter block
#define HT 1024          // threads, histogram kernel
#define FT 1024          // threads, fused accumulate+node kernel
#define S_LOG 8
#define S 256            // nodes per bucket
#define CAP 8912         // records per bucket (mean 8192 + 8 sigma)
#define MAXB 512         // bucket-array bound == ST (one entry per thread!)

__device__ __forceinline__ void gAtomAdd(float* p, float v) {
    unsafeAtomicAdd(p, v);  // hardware global_atomic_add_f32
}

// Init bucket cursors to fixed bases + zero g.
__global__ void k_init(int* __restrict__ cur_d, int* __restrict__ cur_s,
                       float* __restrict__ g, int nb) {
    int t = threadIdx.x;
    if (t < nb) { cur_d[t] = t * CAP; cur_s[t] = t * CAP; }
    if (t < 64) g[t] = 0.0f;
}

// Fused double bucket-scatter, RANK-FIRST (1 LDS atomic per record per phase).
// rec[pos] = (pay << 8) | (key & 255), grouped by key>>8 at fixed bucket bases.
// Scan = wave-local shfl inclusive scan + 8-entry cross-wave fixup.
__global__ void __launch_bounds__(ST) k_sctr2(
        const int4* __restrict__ src4, const int4* __restrict__ dst4, int E,
        int* __restrict__ cur_d, int* __restrict__ cur_s,
        unsigned* __restrict__ rec_d, unsigned* __restrict__ rec_s, int nb) {
    __shared__ unsigned lrec[EPB];          // 32 KB
    __shared__ unsigned short lbkt[EPB];    // 16 KB
    __shared__ int cnt[MAXB];               // rank cursor -> count
    __shared__ int lst[MAXB];               // local run start
    __shared__ int gb[MAXB];                // global run base
    __shared__ int wsum[8];                 // per-wave scan totals
    int t = threadIdx.x;
    int lane = t & 63, wv = t >> 6;
    int E4 = E >> 2;
    int b4 = blockIdx.x * (EPB / 4);
    int m = min(EPB, E - blockIdx.x * EPB);

    int4 dk[4], sk[4];
    bool v[4];
    #pragma unroll
    for (int k = 0; k < 4; ++k) {
        int idx = b4 + k * ST + t;
        v[k] = idx < E4;
        if (v[k]) { dk[k] = dst4[idx]; sk[k] = src4[idx]; }
    }

    for (int ph = 0; ph < 2; ++ph) {        // 0: by dst (pay src); 1: by src (pay dst)
        int* cursor = ph ? cur_s : cur_d;
        unsigned* rec = ph ? rec_s : rec_d;
        cnt[t] = 0;                         // t covers all MAXB entries (MAXB==ST)
        __syncthreads();
        int rk[16];
        #pragma unroll
        for (int k = 0; k < 4; ++k) {
            if (v[k]) {
                int4 K = ph ? sk[k] : dk[k];
                rk[4 * k + 0] = atomicAdd(&cnt[K.x >> S_LOG], 1);
                rk[4 * k + 1] = atomicAdd(&cnt[K.y >> S_LOG], 1);
                rk[4 * k + 2] = atomicAdd(&cnt[K.z >> S_LOG], 1);
                rk[4 * k + 3] = atomicAdd(&cnt[K.w >> S_LOG], 1);
            }
        }
        __syncthreads();
        // block-inclusive scan of cnt[512]: wave shfl scan + cross-wave fixup
        int c = cnt[t];
        int ic = c;
        #pragma unroll
        for (int o = 1; o < 64; o <<= 1) {
            int u = __shfl_up(ic, o);
            if (lane >= o) ic += u;
        }
        if (lane == 63) wsum[wv] = ic;
        __syncthreads();
        int pre = 0;
        #pragma unroll
        for (int k = 0; k < 7; ++k) pre += (k < wv) ? wsum[k] : 0;
        ic += pre;
        lst[t] = ic - c;
        gb[t] = (c > 0) ? atomicAdd(&cursor[t], c) : 0;
        __syncthreads();
        // place records bucket-ordered in LDS at lst[b] + rank
        #pragma unroll
        for (int k = 0; k < 4; ++k) {
            if (v[k]) {
                int4 K = ph ? sk[k] : dk[k];
                int4 P = ph ? dk[k] : sk[k];
                int bb, p;
                bb = K.x >> S_LOG; p = lst[bb] + rk[4 * k + 0];
                lrec[p] = ((unsigned)P.x << S_LOG) | (unsigned)(K.x & (S - 1));
                lbkt[p] = (unsigned short)bb;
                bb = K.y >> S_LOG; p = lst[bb] + rk[4 * k + 1];
                lrec[p] = ((unsigned)P.y << S_LOG) | (unsigned)(K.y & (S - 1));
                lbkt[p] = (unsigned short)bb;
                bb = K.z >> S_LOG; p = lst[bb] + rk[4 * k + 2];
                lrec[p] = ((unsigned)P.z << S_LOG) | (unsigned)(K.z & (S - 1));
                lbkt[p] = (unsigned short)bb;
                bb = K.w >> S_LOG; p = lst[bb] + rk[4 * k + 3];
                lrec[p] = ((unsigned)P.w << S_LOG) | (unsigned)(K.w & (S - 1));
                lbkt[p] = (unsigned short)bb;
            }
        }
        __syncthreads();
        // coalesced flush: one contiguous global run per bucket
        for (int i = t; i < m; i += ST) {
            int bb = lbkt[i];
            rec[gb[bb] + (i - lst[bb])] = lrec[i];
        }
        __syncthreads();
    }
}

// Per dst-bucket: pure node histogram -> dinv + y = dinv*x.
__global__ void __launch_bounds__(HT) k_hist(
        const unsigned* __restrict__ rec_d, const int* __restrict__ cur_d,
        const float4* __restrict__ x, float* __restrict__ dinv,
        float4* __restrict__ y, int n) {
    __shared__ int cnt[S];
    int b = blockIdx.x, t = threadIdx.x;
    if (t < S) cnt[t] = 0;
    __syncthreads();
    int lo = b * CAP;
    int m = cur_d[b] - lo;
    int m4 = m >> 2;
    const uint4* rec4 = (const uint4*)(rec_d + lo);
    for (int i = t; i < m4; i += HT) {
        uint4 r = rec4[i];
        atomicAdd(&cnt[r.x & (S - 1)], 1);
        atomicAdd(&cnt[r.y & (S - 1)], 1);
        atomicAdd(&cnt[r.z & (S - 1)], 1);
        atomicAdd(&cnt[r.w & (S - 1)], 1);
    }
    for (int i = (m4 << 2) + t; i < m; i += HT)
        atomicAdd(&cnt[rec_d[lo + i] & (S - 1)], 1);
    __syncthreads();
    int nd = (b << S_LOG) + t;
    if (t < S && nd < n) {
        float dv = rsqrtf((float)cnt[t] + 1.0f);   // +1 = self loop
        dinv[nd] = dv;
        float4 xi = x[nd];
        y[nd] = make_float4(dv * xi.x, dv * xi.y, dv * xi.z, dv * xi.w);
    }
}

// Per bucket, fused, NO SORT: p1 accumulated by direct LDS float atomics in
// CHANNEL-MAJOR layout (c0..c3[256]: bank = loc&31, all 32 banks -- the
// round-1 failure was node-major lp1[loc][4] = 8 banks/channel);
// sumd via scalar LDS atomics; then matvec + relu + weighted g-reduce.
__global__ void __launch_bounds__(FT) k_fuse(
        const unsigned* __restrict__ rec_d, const unsigned* __restrict__ rec_s,
        const int* __restrict__ cur_d, const int* __restrict__ cur_s,
        const float4* __restrict__ y, const float* __restrict__ dinv,
        const float* __restrict__ W1, const float* __restrict__ b1,
        float* __restrict__ g, int n) {
    __shared__ float c0[S], c1[S], c2[S], c3[S];  // channel-major p1
    __shared__ float a[S];                        // sumd
    __shared__ float red[FT];
    int b = blockIdx.x, t = threadIdx.x;
    if (t < S) { c0[t] = 0.0f; c1[t] = 0.0f; c2[t] = 0.0f; c3[t] = 0.0f; a[t] = 0.0f; }
    __syncthreads();
    int lo = b * CAP;
    int md = cur_d[b] - lo;
    int ms = cur_s[b] - lo;
    int md4 = md >> 2, ms4 = ms >> 2;
    const uint4* rd4 = (const uint4*)(rec_d + lo);
    const uint4* rs4 = (const uint4*)(rec_s + lo);
    // sweep rec_d: p1[loc] += y[src]  (4 channel atomics, conflict-free banks)
    for (int i = t; i < md4; i += FT) {
        uint4 r = rd4[i];
        float4 ya = y[r.x >> S_LOG], yb = y[r.y >> S_LOG];
        float4 yc = y[r.z >> S_LOG], yd = y[r.w >> S_LOG];
        int la = r.x & (S - 1), lb = r.y & (S - 1);
        int lc = r.z & (S - 1), ld = r.w & (S - 1);
        atomicAdd(&c0[la], ya.x); atomicAdd(&c1[la], ya.y);
        atomicAdd(&c2[la], ya.z); atomicAdd(&c3[la], ya.w);
        atomicAdd(&c0[lb], yb.x); atomicAdd(&c1[lb], yb.y);
        atomicAdd(&c2[lb], yb.z); atomicAdd(&c3[lb], yb.w);
        atomicAdd(&c0[lc], yc.x); atomicAdd(&c1[lc], yc.y);
        atomicAdd(&c2[lc], yc.z); atomicAdd(&c3[lc], yc.w);
        atomicAdd(&c0[ld], yd.x); atomicAdd(&c1[ld], yd.y);
        atomicAdd(&c2[ld], yd.z); atomicAdd(&c3[ld], yd.w);
    }
    for (int i = (md4 << 2) + t; i < md; i += FT) {
        unsigned r = rec_d[lo + i];
        float4 ys = y[r >> S_LOG];
        int l = r & (S - 1);
        atomicAdd(&c0[l], ys.x); atomicAdd(&c1[l], ys.y);
        atomicAdd(&c2[l], ys.z); atomicAdd(&c3[l], ys.w);
    }
    // sweep rec_s: sumd[loc] += dinv[dst]
    for (int i = t; i < ms4; i += FT) {
        uint4 r = rs4[i];
        float d0 = dinv[r.x >> S_LOG], d1 = dinv[r.y >> S_LOG];
        float d2 = dinv[r.z >> S_LOG], d3 = dinv[r.w >> S_LOG];
        atomicAdd(&a[r.x & (S - 1)], d0);
        atomicAdd(&a[r.y & (S - 1)], d1);
        atomicAdd(&a[r.z & (S - 1)], d2);
        atomicAdd(&a[r.w & (S - 1)], d3);
    }
    for (int i = (ms4 << 2) + t; i < ms; i += FT) {
        unsigned r = rec_s[lo + i];
        atomicAdd(&a[r & (S - 1)], dinv[r >> S_LOG]);
    }
    __syncthreads();
    // matvec + relu + weighted reduce; wave w: nodes w, w+16, ...; lane = channel
    int cch = t & 63, w = t >> 6;
    float w0 = W1[cch], w1 = W1[64 + cch], w2 = W1[128 + cch], w3 = W1[192 + cch];
    float bb = b1[cch];
    int nb0 = b << S_LOG;
    float facc = 0.0f;
    for (int k = w; k < S; k += 16) {
        int ndk = nb0 + k;
        if (ndk >= n) break;
        float di = dinv[ndk];
        float4 yi = y[ndk];                 // self-loop term: d2*x == di*y
        float h0 = di * (c0[k] + yi.x);     // LDS reads broadcast (same k per wave)
        float h1 = di * (c1[k] + yi.y);
        float h2 = di * (c2[k] + yi.z);
        float h3 = di * (c3[k] + yi.w);
        float h = fmaf(h0, w0, fmaf(h1, w1, fmaf(h2, w2, fmaf(h3, w3, bb))));
        h = fmaxf(h, 0.0f);                 // relu(layer-1 output)
        float wi = fmaf(di, a[k], di * di); // node weight (incl. self loop)
        facc = fmaf(wi, h, facc);
    }
    red[t] = facc;
    __syncthreads();
    if (t < 64) {
        float s = red[t];
        #pragma unroll
        for (int o = 1; o < 16; ++o) s += red[t + 64 * o];
        gAtomAdd(&g[t], s);
    }
}

// out[j] = b2[j] + (g @ W2)[j] / n
__global__ void k_final(const float* __restrict__ g, const float* __restrict__ W2,
                        const float* __restrict__ b2, float* __restrict__ out, float inv_n) {
    int j = threadIdx.x;
    if (j < 32) {
        float a = 0.0f;
        #pragma unroll
        for (int c = 0; c < 64; ++c) a = fmaf(g[c], W2[c * 32 + j], a);
        out[j] = fmaf(a, inv_n, b2[j]);
    }
}

extern "C" void kernel_launch(void* const* d_in, const int* in_sizes, int n_in,
                              void* d_out, int out_size, void* d_ws, size_t ws_size,
                              hipStream_t stream) {
    const float* x  = (const float*)d_in[0];
    const int*   ei = (const int*)d_in[1];
    const float* W1 = (const float*)d_in[2];
    const float* b1 = (const float*)d_in[3];
    const float* W2 = (const float*)d_in[4];
    const float* b2 = (const float*)d_in[5];
    float* out = (float*)d_out;

    int n = in_sizes[0] / 4;      // 100000
    int E = in_sizes[1] / 2;      // 3200000 (multiple of 4)
    const int* src = ei;
    const int* dst = ei + E;
    int NB = (n + S - 1) >> S_LOG;    // 391 buckets

    // workspace (4-byte words), ~30 MB of ~256 MB:
    // cur_d[512] | cur_s[512] | g[64] | pad->1600 | rec_d[NB*CAP] | rec_s[NB*CAP]
    // | y[4n] | dinv[n]
    char* ws = (char*)d_ws;
    int* cur_d = (int*)ws;                 // 512
    int* cur_s = cur_d + 512;              // 512
    float* g   = (float*)(cur_s + 512);    // 64
    size_t ctrl = 1600;                    // words (keeps rec/y 16B-aligned)
    unsigned* rec_d = (unsigned*)ws + ctrl;
    unsigned* rec_s = rec_d + (size_t)NB * CAP;
    float* y    = (float*)(rec_s + (size_t)NB * CAP);   // 4n
    float* dinv = y + 4 * (size_t)n;                    // n

    int NSB = (E + EPB - 1) / EPB;    // 391 scatter blocks

    k_init<<<1, 512, 0, stream>>>(cur_d, cur_s, g, NB);
    k_sctr2<<<NSB, ST, 0, stream>>>((const int4*)src, (const int4*)dst, E,
                                    cur_d, cur_s, rec_d, rec_s, NB);
    k_hist<<<NB, HT, 0, stream>>>(rec_d, cur_d, (const float4*)x, dinv,
                                  (float4*)y, n);
    k_fuse<<<NB, FT, 0, stream>>>(rec_d, rec_s, cur_d, cur_s,
                                  (const float4*)y, dinv, W1, b1, g, n);
    k_final<<<1, 64, 0, stream>>>(g, W2, b2, out, 1.0f / (float)n);
}

// Round 10
// 145.776 us; speedup vs baseline: 1.5155x; 1.5155x over previous
//
#include <hip/hip_runtime.h>

#define ST 512           // threads, scatter kernel
#define EPB 8192         // edges per scatter block
#define HT 1024          // threads, histogram kernel
#define FT 1024          // threads, fused sort+sumd+gather+node kernel
#define S_LOG 8
#define S 256            // nodes per bucket
#define CAP 8912         // records per bucket (mean 8192 + 8 sigma)
#define MAXB 512         // bucket-array bound == ST (one entry per thread!)
#define FXS 8388608.0f   // 2^23 fixed-point scale for sumd
#define FXI 1.1920929e-7f // 2^-23

__device__ __forceinline__ void gAtomAdd(float* p, float v) {
    unsafeAtomicAdd(p, v);  // hardware global_atomic_add_f32
}

// Init bucket cursors to fixed bases + zero g.
__global__ void k_init(int* __restrict__ cur_d, int* __restrict__ cur_s,
                       float* __restrict__ g, int nb) {
    int t = threadIdx.x;
    if (t < nb) { cur_d[t] = t * CAP; cur_s[t] = t * CAP; }
    if (t < 64) g[t] = 0.0f;
}

// Fused double bucket-scatter, RANK-FIRST (1 LDS atomic per record per phase).
// rec[pos] = (pay << 8) | (key & 255), grouped by key>>8 at fixed bucket bases.
// Scan = wave-local shfl inclusive scan + 8-entry cross-wave fixup.
__global__ void __launch_bounds__(ST) k_sctr2(
        const int4* __restrict__ src4, const int4* __restrict__ dst4, int E,
        int* __restrict__ cur_d, int* __restrict__ cur_s,
        unsigned* __restrict__ rec_d, unsigned* __restrict__ rec_s, int nb) {
    __shared__ unsigned lrec[EPB];          // 32 KB
    __shared__ unsigned short lbkt[EPB];    // 16 KB
    __shared__ int cnt[MAXB];               // rank cursor -> count
    __shared__ int lst[MAXB];               // local run start
    __shared__ int gb[MAXB];                // global run base
    __shared__ int wsum[8];                 // per-wave scan totals
    int t = threadIdx.x;
    int lane = t & 63, wv = t >> 6;
    int E4 = E >> 2;
    int b4 = blockIdx.x * (EPB / 4);
    int m = min(EPB, E - blockIdx.x * EPB);

    int4 dk[4], sk[4];
    bool v[4];
    #pragma unroll
    for (int k = 0; k < 4; ++k) {
        int idx = b4 + k * ST + t;
        v[k] = idx < E4;
        if (v[k]) { dk[k] = dst4[idx]; sk[k] = src4[idx]; }
    }

    for (int ph = 0; ph < 2; ++ph) {        // 0: by dst (pay src); 1: by src (pay dst)
        int* cursor = ph ? cur_s : cur_d;
        unsigned* rec = ph ? rec_s : rec_d;
        cnt[t] = 0;                         // t covers all MAXB entries (MAXB==ST)
        __syncthreads();
        int rk[16];
        #pragma unroll
        for (int k = 0; k < 4; ++k) {
            if (v[k]) {
                int4 K = ph ? sk[k] : dk[k];
                rk[4 * k + 0] = atomicAdd(&cnt[K.x >> S_LOG], 1);
                rk[4 * k + 1] = atomicAdd(&cnt[K.y >> S_LOG], 1);
                rk[4 * k + 2] = atomicAdd(&cnt[K.z >> S_LOG], 1);
                rk[4 * k + 3] = atomicAdd(&cnt[K.w >> S_LOG], 1);
            }
        }
        __syncthreads();
        // block-inclusive scan of cnt[512]: wave shfl scan + cross-wave fixup
        int c = cnt[t];
        int ic = c;
        #pragma unroll
        for (int o = 1; o < 64; o <<= 1) {
            int u = __shfl_up(ic, o);
            if (lane >= o) ic += u;
        }
        if (lane == 63) wsum[wv] = ic;
        __syncthreads();
        int pre = 0;
        #pragma unroll
        for (int k = 0; k < 7; ++k) pre += (k < wv) ? wsum[k] : 0;
        ic += pre;
        lst[t] = ic - c;
        gb[t] = (c > 0) ? atomicAdd(&cursor[t], c) : 0;
        __syncthreads();
        // place records bucket-ordered in LDS at lst[b] + rank
        #pragma unroll
        for (int k = 0; k < 4; ++k) {
            if (v[k]) {
                int4 K = ph ? sk[k] : dk[k];
                int4 P = ph ? dk[k] : sk[k];
                int bb, p;
                bb = K.x >> S_LOG; p = lst[bb] + rk[4 * k + 0];
                lrec[p] = ((unsigned)P.x << S_LOG) | (unsigned)(K.x & (S - 1));
                lbkt[p] = (unsigned short)bb;
                bb = K.y >> S_LOG; p = lst[bb] + rk[4 * k + 1];
                lrec[p] = ((unsigned)P.y << S_LOG) | (unsigned)(K.y & (S - 1));
                lbkt[p] = (unsigned short)bb;
                bb = K.z >> S_LOG; p = lst[bb] + rk[4 * k + 2];
                lrec[p] = ((unsigned)P.z << S_LOG) | (unsigned)(K.z & (S - 1));
                lbkt[p] = (unsigned short)bb;
                bb = K.w >> S_LOG; p = lst[bb] + rk[4 * k + 3];
                lrec[p] = ((unsigned)P.w << S_LOG) | (unsigned)(K.w & (S - 1));
                lbkt[p] = (unsigned short)bb;
            }
        }
        __syncthreads();
        // coalesced flush: one contiguous global run per bucket
        for (int i = t; i < m; i += ST) {
            int bb = lbkt[i];
            rec[gb[bb] + (i - lst[bb])] = lrec[i];
        }
        __syncthreads();
    }
}

// Per dst-bucket: pure node histogram -> dinv + y = dinv*x.
__global__ void __launch_bounds__(HT) k_hist(
        const unsigned* __restrict__ rec_d, const int* __restrict__ cur_d,
        const float4* __restrict__ x, float* __restrict__ dinv,
        float4* __restrict__ y, int n) {
    __shared__ int cnt[S];
    int b = blockIdx.x, t = threadIdx.x;
    if (t < S) cnt[t] = 0;
    __syncthreads();
    int lo = b * CAP;
    int m = cur_d[b] - lo;
    int m4 = m >> 2;
    const uint4* rec4 = (const uint4*)(rec_d + lo);
    for (int i = t; i < m4; i += HT) {
        uint4 r = rec4[i];
        atomicAdd(&cnt[r.x & (S - 1)], 1);
        atomicAdd(&cnt[r.y & (S - 1)], 1);
        atomicAdd(&cnt[r.z & (S - 1)], 1);
        atomicAdd(&cnt[r.w & (S - 1)], 1);
    }
    for (int i = (m4 << 2) + t; i < m; i += HT)
        atomicAdd(&cnt[rec_d[lo + i] & (S - 1)], 1);
    __syncthreads();
    int nd = (b << S_LOG) + t;
    if (t < S && nd < n) {
        float dv = rsqrtf((float)cnt[t] + 1.0f);   // +1 = self loop
        dinv[nd] = dv;
        float4 xi = x[nd];
        y[nd] = make_float4(dv * xi.x, dv * xi.y, dv * xi.z, dv * xi.w);
    }
}

// Per bucket, fused: rank-first sort of rec_d into LDS (node-grouped), sumd
// from rec_s via FIXED-POINT INT LDS atomics (native ds_add_u32; float LDS
// atomicAdd measured ~3x slower, layout-independent -- rounds 1/9), CSR
// y-gather (4 thr/node, zero atomics), matvec + relu + weighted g-reduce.
__global__ void __launch_bounds__(FT) k_fuse(
        const unsigned* __restrict__ rec_d, const unsigned* __restrict__ rec_s,
        const int* __restrict__ cur_d, const int* __restrict__ cur_s,
        const float4* __restrict__ y, const float* __restrict__ dinv,
        const float* __restrict__ W1, const float* __restrict__ b1,
        float* __restrict__ g, int n) {
    __shared__ unsigned lrec[CAP];   // node-sorted src ids (35.6 KB)
    __shared__ int cnt[S];           // histogram -> inclusive ends
    __shared__ int nst[S];           // starts
    __shared__ int ia[S];            // sumd, fixed-point 2^23
    __shared__ float4 lp1[S];
    __shared__ float red[FT];
    __shared__ int wsum[4];
    int b = blockIdx.x, t = threadIdx.x;
    int lane = t & 63, wv = t >> 6;
    if (t < S) { cnt[t] = 0; ia[t] = 0; }
    __syncthreads();
    int lo = b * CAP;
    // rank-first histogram of dst-grouped records (ranks in regs)
    int md = cur_d[b] - lo;
    unsigned rv[9]; int rr[9];
    #pragma unroll
    for (int k = 0; k < 9; ++k) {
        int i = t + k * FT;
        if (i < md) {
            unsigned r = rec_d[lo + i];
            rv[k] = r;
            rr[k] = atomicAdd(&cnt[r & (S - 1)], 1);
        }
    }
    __syncthreads();
    // inclusive scan of cnt[256]: waves 0..3 shfl scan + 4-entry fixup
    int c = 0, ic = 0;
    if (t < S) {
        c = cnt[t]; ic = c;
        #pragma unroll
        for (int o = 1; o < 64; o <<= 1) {
            int u = __shfl_up(ic, o);
            if (lane >= o) ic += u;
        }
        if (lane == 63) wsum[wv] = ic;
    }
    __syncthreads();
    if (t < S) {
        int pre = 0;
        #pragma unroll
        for (int k = 0; k < 3; ++k) pre += (k < wv) ? wsum[k] : 0;
        ic += pre;
        cnt[t] = ic;        // inclusive end per node
        nst[t] = ic - c;    // start per node
    }
    __syncthreads();
    // place src ids node-grouped in LDS
    #pragma unroll
    for (int k = 0; k < 9; ++k) {
        int i = t + k * FT;
        if (i < md) lrec[nst[rv[k] & (S - 1)] + rr[k]] = rv[k] >> S_LOG;
    }
    // sumd[loc] += dinv[dst] over src-grouped records (fixed-point int atomics)
    int ms = cur_s[b] - lo;
    int ms4 = ms >> 2;
    const uint4* rs4 = (const uint4*)(rec_s + lo);
    for (int i = t; i < ms4; i += FT) {
        uint4 r = rs4[i];
        int d0 = (int)(dinv[r.x >> S_LOG] * FXS + 0.5f);
        int d1 = (int)(dinv[r.y >> S_LOG] * FXS + 0.5f);
        int d2 = (int)(dinv[r.z >> S_LOG] * FXS + 0.5f);
        int d3 = (int)(dinv[r.w >> S_LOG] * FXS + 0.5f);
        atomicAdd(&ia[r.x & (S - 1)], d0);
        atomicAdd(&ia[r.y & (S - 1)], d1);
        atomicAdd(&ia[r.z & (S - 1)], d2);
        atomicAdd(&ia[r.w & (S - 1)], d3);
    }
    for (int i = (ms4 << 2) + t; i < ms; i += FT) {
        unsigned r = rec_s[lo + i];
        atomicAdd(&ia[r & (S - 1)], (int)(dinv[r >> S_LOG] * FXS + 0.5f));
    }
    __syncthreads();
    // CSR y-gather: 4 threads/node, batched float4 gathers, shfl reduce
    int node = t >> 2, q = t & 3;
    int nd = (b << S_LOG) + node;
    if (nd < n) {
        int j1 = cnt[node];
        int j = nst[node] + q;
        float a0 = 0.0f, a1 = 0.0f, a2 = 0.0f, a3 = 0.0f;
        for (; j + 12 < j1; j += 16) {
            int s0 = lrec[j], s1 = lrec[j + 4], s2 = lrec[j + 8], s3 = lrec[j + 12];
            float4 y0 = y[s0], y1 = y[s1], y2 = y[s2], y3 = y[s3];
            a0 += y0.x + y1.x + y2.x + y3.x;
            a1 += y0.y + y1.y + y2.y + y3.y;
            a2 += y0.z + y1.z + y2.z + y3.z;
            a3 += y0.w + y1.w + y2.w + y3.w;
        }
        for (; j < j1; j += 4) {
            float4 ys = y[lrec[j]];
            a0 += ys.x; a1 += ys.y; a2 += ys.z; a3 += ys.w;
        }
        a0 += __shfl_down(a0, 2); a1 += __shfl_down(a1, 2);
        a2 += __shfl_down(a2, 2); a3 += __shfl_down(a3, 2);
        a0 += __shfl_down(a0, 1); a1 += __shfl_down(a1, 1);
        a2 += __shfl_down(a2, 1); a3 += __shfl_down(a3, 1);
        if (q == 0) {
            float di = dinv[nd];
            lp1[node] = make_float4(di * a0, di * a1, di * a2, di * a3);
        }
    }
    __syncthreads();
    // matvec + relu + weighted reduce; wave w: nodes w, w+16, ...; lane = channel
    int cch = t & 63, w = t >> 6;
    float w0 = W1[cch], w1 = W1[64 + cch], w2 = W1[128 + cch], w3 = W1[192 + cch];
    float bb = b1[cch];
    int nb0 = b << S_LOG;
    float facc = 0.0f;
    for (int k = w; k < S; k += 16) {
        int ndk = nb0 + k;
        if (ndk >= n) break;
        float di = dinv[ndk];
        float4 p = lp1[k];
        float4 yi = y[ndk];                 // self-loop term: d2*x == di*y
        float h0 = fmaf(di, yi.x, p.x);
        float h1 = fmaf(di, yi.y, p.y);
        float h2 = fmaf(di, yi.z, p.z);
        float h3 = fmaf(di, yi.w, p.w);
        float h = fmaf(h0, w0, fmaf(h1, w1, fmaf(h2, w2, fmaf(h3, w3, bb))));
        h = fmaxf(h, 0.0f);                 // relu(layer-1 output)
        float ak = (float)ia[k] * FXI;      // back to float
        float wi = fmaf(di, ak, di * di);   // node weight (incl. self loop)
        facc = fmaf(wi, h, facc);
    }
    red[t] = facc;
    __syncthreads();
    if (t < 64) {
        float s = red[t];
        #pragma unroll
        for (int o = 1; o < 16; ++o) s += red[t + 64 * o];
        gAtomAdd(&g[t], s);
    }
}

// out[j] = b2[j] + (g @ W2)[j] / n
__global__ void k_final(const float* __restrict__ g, const float* __restrict__ W2,
                        const float* __restrict__ b2, float* __restrict__ out, float inv_n) {
    int j = threadIdx.x;
    if (j < 32) {
        float a = 0.0f;
        #pragma unroll
        for (int c = 0; c < 64; ++c) a = fmaf(g[c], W2[c * 32 + j], a);
        out[j] = fmaf(a, inv_n, b2[j]);
    }
}

extern "C" void kernel_launch(void* const* d_in, const int* in_sizes, int n_in,
                              void* d_out, int out_size, void* d_ws, size_t ws_size,
                              hipStream_t stream) {
    const float* x  = (const float*)d_in[0];
    const int*   ei = (const int*)d_in[1];
    const float* W1 = (const float*)d_in[2];
    const float* b1 = (const float*)d_in[3];
    const float* W2 = (const float*)d_in[4];
    const float* b2 = (const float*)d_in[5];
    float* out = (float*)d_out;

    int n = in_sizes[0] / 4;      // 100000
    int E = in_sizes[1] / 2;      // 3200000 (multiple of 4)
    const int* src = ei;
    const int* dst = ei + E;
    int NB = (n + S - 1) >> S_LOG;    // 391 buckets

    // workspace (4-byte words), ~30 MB of ~256 MB:
    // cur_d[512] | cur_s[512] | g[64] | pad->1600 | rec_d[NB*CAP] | rec_s[NB*CAP]
    // | y[4n] | dinv[n]
    char* ws = (char*)d_ws;
    int* cur_d = (int*)ws;                 // 512
    int* cur_s = cur_d + 512;              // 512
    float* g   = (float*)(cur_s + 512);    // 64
    size_t ctrl = 1600;                    // words (keeps rec/y 16B-aligned)
    unsigned* rec_d = (unsigned*)ws + ctrl;
    unsigned* rec_s = rec_d + (size_t)NB * CAP;
    float* y    = (float*)(rec_s + (size_t)NB * CAP);   // 4n
    float* dinv = y + 4 * (size_t)n;                    // n

    int NSB = (E + EPB - 1) / EPB;    // 391 scatter blocks

    k_init<<<1, 512, 0, stream>>>(cur_d, cur_s, g, NB);
    k_sctr2<<<NSB, ST, 0, stream>>>((const int4*)src, (const int4*)dst, E,
                                    cur_d, cur_s, rec_d, rec_s, NB);
    k_hist<<<NB, HT, 0, stream>>>(rec_d, cur_d, (const float4*)x, dinv,
                                  (float4*)y, n);
    k_fuse<<<NB, FT, 0, stream>>>(rec_d, rec_s, cur_d, cur_s,
                                  (const float4*)y, dinv, W1, b1, g, n);
    k_final<<<1, 64, 0, stream>>>(g, W2, b2, out, 1.0f / (float)n);
}